// Round 18
// baseline (37.433 us; speedup 1.0000x reference)
//
#include <hip/hip_runtime.h>
#include <math.h>

#define NPTS 1000
#define NGRID 256
#define PI_D 3.14159265358979323846
#define MAGICU 0x5A5A5A5Au

// Y grid: linspace(1e-3, 0.999, 1000). YD grid: linspace(1e-3, 1.0, 1000).
#define HY   ((0.999 - 1e-3) / 999.0)
#define Y0C  (1e-3)
#define HD   ((1.0 - 1e-3) / 999.0)

// trapz+extrapolation weights (closed form — uniform grid)
#define WY0   (0.5 * HY + Y0C + 0.5 * Y0C * Y0C / HY)
#define WY1   (HY - 0.5 * Y0C * Y0C / HY)
#define WY999 (0.5 * HY + 0.5 * (1.0 - 0.999))
#define WD0   (0.5 * (Y0C + HD))
#define WD999 (0.5 * HD)

struct SCf {
    float c[11], pc[11], bc[6], dbc[5], S, sa;
};

__device__ inline void make_scf(const float* a, const float* b, SCf& s) {
    float af[6], bf[6];
    af[0] = 1.0f; bf[0] = 1.0f;
    #pragma unroll
    for (int i = 0; i < 5; ++i) { af[i+1] = a[i]; bf[i+1] = b[i]; }
    #pragma unroll
    for (int k = 0; k < 11; ++k) s.c[k] = 0.0f;
    #pragma unroll
    for (int i = 0; i < 6; ++i)
        #pragma unroll
        for (int j = 0; j < 6; ++j)
            s.c[i+j] = fmaf(4.0f * af[i], af[j], s.c[i+j]);
    const float INVK[11] = { -0.25f, -1.0f/3.0f, -0.5f, -1.0f, 0.0f,
                              1.0f, 0.5f, 1.0f/3.0f, 0.25f, 0.2f, 1.0f/6.0f };
    float S = 0.0f;
    #pragma unroll
    for (int k = 0; k < 11; ++k) { s.pc[k] = s.c[k] * INVK[k]; S += s.pc[k]; }
    s.S = S;
    float sa = 0.0f;
    #pragma unroll
    for (int i = 0; i < 5; ++i) sa = fmaf(a[i], a[i], sa);
    s.sa = sa;
    #pragma unroll
    for (int i = 0; i < 6; ++i) s.bc[i] = bf[i];
    #pragma unroll
    for (int i = 1; i < 6; ++i) s.dbc[i-1] = (float)i * bf[i];
}

__device__ inline float eval_f_f(float z, float lnz, float z4, const SCf& s) {
    float P = s.pc[10];
    #pragma unroll
    for (int k = 9; k >= 0; --k) P = fmaf(P, z, s.pc[k]);
    return s.S * z4 - P - s.c[4] * z4 * lnz + 0.004f * s.sa * z4 * (1.0f - z);
}
__device__ inline float eval_Q_f(float z, const SCf& s) {
    float Q = s.c[10];
    #pragma unroll
    for (int k = 9; k >= 0; --k) Q = fmaf(Q, z, s.c[k]);
    return Q;
}
__device__ inline float eval_bv_f(float z, const SCf& s) {
    float B = s.bc[5];
    #pragma unroll
    for (int k = 4; k >= 0; --k) B = fmaf(B, z, s.bc[k]);
    return B;
}
__device__ inline float eval_dbv_f(float z, const SCf& s) {
    float D = s.dbc[4];
    #pragma unroll
    for (int k = 3; k >= 0; --k) D = fmaf(D, z, s.dbc[k]);
    return D;
}

struct PtCf { float y, u, lnu, wt, inv_u; };
struct ItSf { float zs, lnzs, zs4, fs, inv_fs, inv_zs, sdf, dfs; };

__device__ inline void make_points(int tid, PtCf* p) {
    #pragma unroll
    for (int j = 0; j < 2; ++j) {
        int k = tid + j * 512;
        int kk = (k < NPTS) ? k : (NPTS - 1);
        float y = (float)(Y0C + (double)kk * HY);
        float u = (1.0f - y) * (1.0f + y);
        p[j].y = y;
        p[j].u = u;
        p[j].lnu = __logf(u);
        p[j].inv_u = __fdividef(1.0f, u);
        float wt;
        if (k >= NPTS)      wt = 0.0f;
        else if (k == 0)    wt = (float)WY0;
        else if (k == 1)    wt = (float)WY1;
        else if (k == 999)  wt = (float)WY999;
        else                wt = (float)HY;
        p[j].wt = wt;
    }
}

__device__ inline void iter_scalars_f(float zs, const SCf& s, ItSf& it) {
    it.zs = zs;
    it.lnzs = __logf(zs);
    float z2 = zs * zs;
    it.zs4 = z2 * z2;
    it.inv_zs = __fdividef(1.0f, zs);
    float f = eval_f_f(zs, it.lnzs, it.zs4, s);
    float Q = eval_Q_f(zs, s);
    float dfs = (4.0f * f - Q) * it.inv_zs - 0.004f * s.sa * it.zs4;
    it.fs = f;
    it.inv_fs = __fdividef(1.0f, f);
    it.dfs = dfs;
    it.sdf = zs * dfs * it.inv_fs;   // zs*dfs/fs
}

// L / dL integrands (grid phase).
__device__ inline void integrands_f(const PtCf& p, const ItSf& is, const SCf& s,
                                    float& IL, float& ID) {
    float u = p.u;
    float w2 = u * u, w4 = w2 * w2;
    float z   = is.zs * u;
    float lnz = is.lnzs + p.lnu;
    float z4  = is.zs4 * w4;
    float f = eval_f_f(z, lnz, z4, s);
    float bv = eval_bv_f(z, s);
    float inv_f = __fdividef(1.0f, f);
    float sqrtg = fabsf(bv) * rsqrtf(f);
    float fofs = f * is.inv_fs;
    float iu2 = p.inv_u * p.inv_u;
    float r4 = iu2 * iu2;                // zs^4/z^4
    float A = fofs * r4;
    float r = rsqrtf(A - 1.0f);
    IL = sqrtg * p.y * r;
    {
        float Q = eval_Q_f(z, s);
        float inv_z = is.inv_zs * p.inv_u;
        float df = (4.0f * f - Q) * inv_z - 0.004f * s.sa * z4;
        float dbv = eval_dbv_f(z, s);
        float t = z * (2.0f * __fdividef(dbv, bv) - df * inv_f);   // z*dg/g
        float i1 = A * (is.sdf + 2.0f + t) - r4 * z * df * is.inv_fs - 2.0f - t;
        ID = i1 * 2.0f * p.y * sqrtg * (r * r * r);
    }
}

// deterministic block reductions (512 threads = 8 waves)
__device__ inline void block_reduce2f(float& sx, float& sy, float2* lds, int tid) {
    #pragma unroll
    for (int off = 32; off > 0; off >>= 1) {
        sx += __shfl_xor(sx, off);
        sy += __shfl_xor(sy, off);
    }
    int wid = tid >> 6;
    if ((tid & 63) == 0) lds[wid] = make_float2(sx, sy);
    __syncthreads();
    float rx = 0.0f, ry = 0.0f;
    #pragma unroll
    for (int w = 0; w < 8; ++w) { rx += lds[w].x; ry += lds[w].y; }
    __syncthreads();
    sx = rx; sy = ry;
}

__device__ inline void block_reduce6f(float* s, float (*lds)[6], int tid) {
    #pragma unroll
    for (int off = 32; off > 0; off >>= 1) {
        #pragma unroll
        for (int i = 0; i < 6; ++i) s[i] += __shfl_xor(s[i], off);
    }
    int wid = tid >> 6;
    if ((tid & 63) == 0) {
        #pragma unroll
        for (int i = 0; i < 6; ++i) lds[wid][i] = s[i];
    }
    __syncthreads();
    #pragma unroll
    for (int i = 0; i < 6; ++i) {
        float r = 0.0f;
        #pragma unroll
        for (int w = 0; w < 8; ++w) r += lds[w][i];
        s[i] = r;
    }
    __syncthreads();
}

__device__ inline double grid_zs(int i) {
    return 0.05 + (double)i * (0.999 - 0.05) / 255.0;
}

// ---------------- Single fused kernel: produce W entry, publish, spin, Newton ----------------
__global__ __launch_bounds__(512, 4) void k_all(const float* Ls, const float* a,
                                                const float* b, const float* logcoef,
                                                float* W, unsigned* ready,
                                                float* out, int out_size, int B) {
    __shared__ float2 red2[8];
    __shared__ float red6[8][6];
    __shared__ float wv[8];
    __shared__ int wi[8];
    int tid = threadIdx.x, blk = blockIdx.x;
    SCf sc;
    make_scf(a, b, sc);
    PtCf p[2];
    make_points(tid, p);

    // ---- PHASE 1: produce grid entry (blk % NGRID); redundant pairs write identical bits ----
    int ge = blk % NGRID;
    {
        float zsg = (float)grid_zs(ge);
        ItSf isg;
        iter_scalars_f(zsg, sc, isg);
        float sLf = 0.0f, sDf = 0.0f;
        #pragma unroll
        for (int j = 0; j < 2; ++j) {
            float IL, ID;
            integrands_f(p[j], isg, sc, IL, ID);
            sLf = fmaf(p[j].wt, IL, sLf);
            sDf = fmaf(p[j].wt, ID, sDf);
        }
        block_reduce2f(sLf, sDf, red2, tid);
        if (tid == 0) {
            float wval = (sDf > 0.0f) ? (float)(4.0 * (double)zsg * (double)sLf / PI_D)
                                      : 1e30f;
            unsigned bits = __float_as_uint(wval);
            __hip_atomic_store((unsigned*)&W[ge], bits,
                               __ATOMIC_RELAXED, __HIP_MEMORY_SCOPE_AGENT);
            __hip_atomic_store(&ready[ge], bits ^ MAGICU,
                               __ATOMIC_RELEASE, __HIP_MEMORY_SCOPE_AGENT);
        }
    }

    if (blk >= B) return;   // producer-only blocks (when B < grid size)

    // ---- PHASE 2: wait for the full table (each tid<256 owns one entry) ----
    float myW = 1e30f;
    if (tid < NGRID) {
        int spins = 0;
        while (true) {
            unsigned r = __hip_atomic_load(&ready[tid],
                                           __ATOMIC_ACQUIRE, __HIP_MEMORY_SCOPE_AGENT);
            unsigned w = __hip_atomic_load((unsigned*)&W[tid],
                                           __ATOMIC_RELAXED, __HIP_MEMORY_SCOPE_AGENT);
            if (r == (w ^ MAGICU)) { myW = __uint_as_float(w); break; }
            if (++spins > (1 << 18)) { myW = __uint_as_float(w); break; }  // escape hatch
            __builtin_amdgcn_s_sleep(1);
        }
    }
    __syncthreads();

    float Ltf = Ls[blk];
    double Lt = (double)Ltf;

    // argmin |W - L| over registers (first-min tie-break)
    float v = (tid < NGRID) ? fabsf(myW - Ltf) : 3e38f;
    int idx = (tid < NGRID) ? tid : (1 << 30);
    #pragma unroll
    for (int off = 32; off > 0; off >>= 1) {
        float ov = __shfl_xor(v, off);
        int oi = __shfl_xor(idx, off);
        if (ov < v || (ov == v && oi < idx)) { v = ov; idx = oi; }
    }
    if ((tid & 63) == 0) { wv[tid >> 6] = v; wi[tid >> 6] = idx; }
    __syncthreads();
    v = wv[0]; idx = wi[0];
    #pragma unroll
    for (int w = 1; w < 8; ++w) {
        if (wv[w] < v || (wv[w] == v && wi[w] < idx)) { v = wv[w]; idx = wi[w]; }
    }

    // Linear-interp init within the bracketing cell (agent-scope loads bypass stale L1).
    double zs = grid_zs(idx);
    {
        unsigned w0b = __hip_atomic_load((unsigned*)&W[idx],
                                         __ATOMIC_RELAXED, __HIP_MEMORY_SCOPE_AGENT);
        float Lg0 = __uint_as_float(w0b);
        if (Lg0 < 1e29f) {
            int nb = (Lg0 <= Ltf) ? idx + 1 : idx - 1;
            if (nb >= 0 && nb < NGRID) {
                unsigned w1b = __hip_atomic_load((unsigned*)&W[nb],
                                                 __ATOMIC_RELAXED, __HIP_MEMORY_SCOPE_AGENT);
                float Lg1 = __uint_as_float(w1b);
                if (Lg1 < 1e29f && Lg1 != Lg0) {
                    float tf = __fdividef(Ltf - Lg0, Lg1 - Lg0);
                    tf = fminf(fmaxf(tf, 0.0f), 1.0f);
                    zs = zs + (double)tf * (grid_zs(nb) - grid_zs(idx));
                }
            }
        }
    }
    __syncthreads();

    // ---- PHASE 3: ONE mega-pass at zs0 (L, dL, Vc, dVc, Vd, dVd) + Taylor output ----
    ItSf is;
    iter_scalars_f((float)zs, sc, is);
    float omzs = 1.0f - (float)zs;
    float s6[6] = {0,0,0,0,0,0};   // sL, sD, sVc, sdVc, sVd, sdVd
    #pragma unroll
    for (int j = 0; j < 2; ++j) {
        int k = tid + j * 512;
        int kk = (k < NPTS) ? k : (NPTS - 1);
        float u = p[j].u;
        float w2 = u * u, w4 = w2 * w2;
        float z   = is.zs * u;
        float lnz = is.lnzs + p[j].lnu;
        float z4  = is.zs4 * w4;
        float f = eval_f_f(z, lnz, z4, sc);
        float bv = eval_bv_f(z, sc);
        float ab = fabsf(bv);
        float sg = copysignf(1.0f, bv);
        float dbv = eval_dbv_f(z, sc);
        float inv_f = __fdividef(1.0f, f);
        float Q = eval_Q_f(z, sc);
        float inv_z = is.inv_zs * p[j].inv_u;
        float df = (4.0f * f - Q) * inv_z - 0.004f * sc.sa * z4;
        float iu2 = p[j].inv_u * p[j].inv_u;
        float r4 = iu2 * iu2;
        {   // L and dL integrands
            float sqrtg = ab * rsqrtf(f);
            float fofs = f * is.inv_fs;
            float A = fofs * r4;
            float r = rsqrtf(A - 1.0f);
            float IL = sqrtg * p[j].y * r;
            float t = z * (2.0f * __fdividef(dbv, bv) - df * inv_f);
            float i1 = A * (is.sdf + 2.0f + t) - r4 * z * df * is.inv_fs - 2.0f - t;
            float ID = i1 * 2.0f * p[j].y * sqrtg * (r * r * r);
            s6[0] = fmaf(p[j].wt, IL, s6[0]);
            s6[1] = fmaf(p[j].wt, ID, s6[1]);
        }
        {   // Vc integrand + d/dzs
            float arg = fmaf(-w4 * is.fs, inv_f, 1.0f);      // 1 - w4*fs/f
            float r = rsqrtf(arg);
            float yiu2 = p[j].y * iu2;
            float Ic = ab * (r - 1.0f) * yiu2;
            float darg = -w4 * inv_f * fmaf(-is.fs * inv_f * df, u, is.dfs);
            float dIc = yiu2 * fmaf(sg * dbv * u, (r - 1.0f),
                                    -0.5f * ab * (r * r * r) * darg);
            s6[2] = fmaf(p[j].wt, Ic, s6[2]);
            s6[3] = fmaf(p[j].wt, dIc, s6[3]);
        }
        {   // Vd integrand + d/dzs (z = 1-(1-zs)*yd)
            float yd = (float)(Y0C + (double)kk * HD);
            float wyd;
            if (k >= NPTS)      wyd = 0.0f;
            else if (k == 0)    wyd = (float)WD0;
            else if (k == 999)  wyd = (float)WD999;
            else                wyd = (float)HD;
            float zd = fmaf(-omzs, yd, 1.0f);
            float bvd = eval_bv_f(zd, sc);
            float abd = fabsf(bvd);
            float sgd = copysignf(1.0f, bvd);
            float dbvd = eval_dbv_f(zd, sc);
            float izd = __fdividef(1.0f, zd);
            float izd2 = izd * izd;
            float Id = abd * izd2;
            float dId = yd * fmaf(sgd * dbvd, zd, -2.0f * abd) * izd2 * izd;
            s6[4] = fmaf(wyd, Id, s6[4]);
            s6[5] = fmaf(wyd, dId, s6[5]);
        }
    }
    block_reduce6f(s6, red6, tid);

    // Scalar epilogue (f64): Newton step + first-order V propagation.
    double L_  = 4.0 * zs * (double)s6[0] / PI_D;
    double dL  = (double)s6[1] / PI_D;
    double zs1 = zs - (L_ - Lt) / dL;
    zs1 = fmin(fmax(zs1, 1e-3), 0.999);
    double dz = zs1 - zs;

    double elc = exp((double)logcoef[0]);
    double Kc = elc * PI_D * 4.0;
    double Kd = elc * PI_D * 2.0;
    double SVc = (double)s6[2], SdVc = (double)s6[3];
    double SVd = (double)s6[4], SdVd = (double)s6[5];
    double C0 = 0.5 * Y0C;
    double Vc  = Kc * SVc / zs;
    double dVc = Kc * (SdVc / zs - SVc / (zs * zs));
    double Vd  = Kd * (1.0 - zs) * (C0 + SVd);
    double dVd = Kd * (-(C0 + SVd) + (1.0 - zs) * SdVd);
    double outv = (Vc - Vd) + dz * (dVc - dVd);

    if (tid == 0) {
        if (out_size >= 2 * B) {   // complex64 layout: interleaved re, im
            out[2 * blk]     = (float)outv;
            out[2 * blk + 1] = 0.0f;
        } else {
            out[blk] = (float)outv;
        }
    }
}

extern "C" void kernel_launch(void* const* d_in, const int* in_sizes, int n_in,
                              void* d_out, int out_size, void* d_ws, size_t ws_size,
                              hipStream_t stream) {
    const float* Ls = (const float*)d_in[0];
    const float* a  = (const float*)d_in[1];
    const float* b  = (const float*)d_in[2];
    const float* lc = (const float*)d_in[3];
    float* W = (float*)d_ws;
    unsigned* ready = (unsigned*)(W + NGRID);
    int B = in_sizes[0];

    int grid = (B > NGRID) ? B : NGRID;
    hipLaunchKernelGGL(k_all, dim3(grid), dim3(512), 0, stream,
                       Ls, a, b, lc, W, ready, (float*)d_out, out_size, B);
}

// Round 19
// 24.519 us; speedup vs baseline: 1.5267x; 1.5267x over previous
//
#include <hip/hip_runtime.h>
#include <math.h>

#define NPTS 1000
#define NGRID 256
#define PI_D 3.14159265358979323846

// Y grid: linspace(1e-3, 0.999, 1000). YD grid: linspace(1e-3, 1.0, 1000).
#define HY   ((0.999 - 1e-3) / 999.0)
#define Y0C  (1e-3)
#define HD   ((1.0 - 1e-3) / 999.0)

// trapz+extrapolation weights (closed form — uniform grid)
#define WY0   (0.5 * HY + Y0C + 0.5 * Y0C * Y0C / HY)
#define WY1   (HY - 0.5 * Y0C * Y0C / HY)
#define WY999 (0.5 * HY + 0.5 * (1.0 - 0.999))
#define WD0   (0.5 * (Y0C + HD))
#define WD999 (0.5 * HD)

struct SCf {
    float c[11], pc[11], bc[6], dbc[5], S, sa;
};

__device__ inline void make_scf(const float* a, const float* b, SCf& s) {
    float af[6], bf[6];
    af[0] = 1.0f; bf[0] = 1.0f;
    #pragma unroll
    for (int i = 0; i < 5; ++i) { af[i+1] = a[i]; bf[i+1] = b[i]; }
    #pragma unroll
    for (int k = 0; k < 11; ++k) s.c[k] = 0.0f;
    #pragma unroll
    for (int i = 0; i < 6; ++i)
        #pragma unroll
        for (int j = 0; j < 6; ++j)
            s.c[i+j] = fmaf(4.0f * af[i], af[j], s.c[i+j]);
    const float INVK[11] = { -0.25f, -1.0f/3.0f, -0.5f, -1.0f, 0.0f,
                              1.0f, 0.5f, 1.0f/3.0f, 0.25f, 0.2f, 1.0f/6.0f };
    float S = 0.0f;
    #pragma unroll
    for (int k = 0; k < 11; ++k) { s.pc[k] = s.c[k] * INVK[k]; S += s.pc[k]; }
    s.S = S;
    float sa = 0.0f;
    #pragma unroll
    for (int i = 0; i < 5; ++i) sa = fmaf(a[i], a[i], sa);
    s.sa = sa;
    #pragma unroll
    for (int i = 0; i < 6; ++i) s.bc[i] = bf[i];
    #pragma unroll
    for (int i = 1; i < 6; ++i) s.dbc[i-1] = (float)i * bf[i];
}

__device__ inline float eval_f_f(float z, float lnz, float z4, const SCf& s) {
    float P = s.pc[10];
    #pragma unroll
    for (int k = 9; k >= 0; --k) P = fmaf(P, z, s.pc[k]);
    return s.S * z4 - P - s.c[4] * z4 * lnz + 0.004f * s.sa * z4 * (1.0f - z);
}
__device__ inline float eval_Q_f(float z, const SCf& s) {
    float Q = s.c[10];
    #pragma unroll
    for (int k = 9; k >= 0; --k) Q = fmaf(Q, z, s.c[k]);
    return Q;
}
__device__ inline float eval_bv_f(float z, const SCf& s) {
    float B = s.bc[5];
    #pragma unroll
    for (int k = 4; k >= 0; --k) B = fmaf(B, z, s.bc[k]);
    return B;
}
__device__ inline float eval_dbv_f(float z, const SCf& s) {
    float D = s.dbc[4];
    #pragma unroll
    for (int k = 3; k >= 0; --k) D = fmaf(D, z, s.dbc[k]);
    return D;
}

struct PtCf { float y, u, lnu, wt, inv_u; };
struct ItSf { float zs, lnzs, zs4, fs, inv_fs, inv_zs, sdf, dfs; };

// ONE point per thread (1024-thread blocks; tid >= NPTS masked by wt=0).
__device__ inline void make_point(int tid, PtCf& p) {
    int kk = (tid < NPTS) ? tid : (NPTS - 1);
    float y = (float)(Y0C + (double)kk * HY);
    float u = (1.0f - y) * (1.0f + y);
    p.y = y;
    p.u = u;
    p.lnu = __logf(u);
    p.inv_u = __fdividef(1.0f, u);
    float wt;
    if (tid >= NPTS)     wt = 0.0f;
    else if (tid == 0)   wt = (float)WY0;
    else if (tid == 1)   wt = (float)WY1;
    else if (tid == 999) wt = (float)WY999;
    else                 wt = (float)HY;
    p.wt = wt;
}

__device__ inline void iter_scalars_f(float zs, const SCf& s, ItSf& it) {
    it.zs = zs;
    it.lnzs = __logf(zs);
    float z2 = zs * zs;
    it.zs4 = z2 * z2;
    it.inv_zs = __fdividef(1.0f, zs);
    float f = eval_f_f(zs, it.lnzs, it.zs4, s);
    float Q = eval_Q_f(zs, s);
    float dfs = (4.0f * f - Q) * it.inv_zs - 0.004f * s.sa * it.zs4;
    it.fs = f;
    it.inv_fs = __fdividef(1.0f, f);
    it.dfs = dfs;
    it.sdf = zs * dfs * it.inv_fs;   // zs*dfs/fs
}

// L / dL integrands (grid kernel).
__device__ inline void integrands_f(const PtCf& p, const ItSf& is, const SCf& s,
                                    float& IL, float& ID) {
    float u = p.u;
    float w2 = u * u, w4 = w2 * w2;
    float z   = is.zs * u;
    float lnz = is.lnzs + p.lnu;
    float z4  = is.zs4 * w4;
    float f = eval_f_f(z, lnz, z4, s);
    float bv = eval_bv_f(z, s);
    float inv_f = __fdividef(1.0f, f);
    float sqrtg = fabsf(bv) * rsqrtf(f);
    float fofs = f * is.inv_fs;
    float iu2 = p.inv_u * p.inv_u;
    float r4 = iu2 * iu2;                // zs^4/z^4
    float A = fofs * r4;
    float r = rsqrtf(A - 1.0f);
    IL = sqrtg * p.y * r;
    {
        float Q = eval_Q_f(z, s);
        float inv_z = is.inv_zs * p.inv_u;
        float df = (4.0f * f - Q) * inv_z - 0.004f * s.sa * z4;
        float dbv = eval_dbv_f(z, s);
        float t = z * (2.0f * __fdividef(dbv, bv) - df * inv_f);   // z*dg/g
        float i1 = A * (is.sdf + 2.0f + t) - r4 * z * df * is.inv_fs - 2.0f - t;
        ID = i1 * 2.0f * p.y * sqrtg * (r * r * r);
    }
}

// deterministic block reductions (1024 threads = 16 waves)
__device__ inline void block_reduce2f(float& sx, float& sy, float2* lds, int tid) {
    #pragma unroll
    for (int off = 32; off > 0; off >>= 1) {
        sx += __shfl_xor(sx, off);
        sy += __shfl_xor(sy, off);
    }
    int wid = tid >> 6;
    if ((tid & 63) == 0) lds[wid] = make_float2(sx, sy);
    __syncthreads();
    float rx = 0.0f, ry = 0.0f;
    #pragma unroll
    for (int w = 0; w < 16; ++w) { rx += lds[w].x; ry += lds[w].y; }
    __syncthreads();
    sx = rx; sy = ry;
}

__device__ inline void block_reduce6f(float* s, float (*lds)[6], int tid) {
    #pragma unroll
    for (int off = 32; off > 0; off >>= 1) {
        #pragma unroll
        for (int i = 0; i < 6; ++i) s[i] += __shfl_xor(s[i], off);
    }
    int wid = tid >> 6;
    if ((tid & 63) == 0) {
        #pragma unroll
        for (int i = 0; i < 6; ++i) lds[wid][i] = s[i];
    }
    __syncthreads();
    #pragma unroll
    for (int i = 0; i < 6; ++i) {
        float r = 0.0f;
        #pragma unroll
        for (int w = 0; w < 16; ++w) r += lds[w][i];
        s[i] = r;
    }
    __syncthreads();
}

__device__ inline double grid_zs(int i) {
    return 0.05 + (double)i * (0.999 - 0.05) / 255.0;
}

// ---- Kernel 1: Lg (masked to rising branch) over a FIXED zs grid ----
__global__ __launch_bounds__(1024, 4) void k_grid(const float* a, const float* b, float* W) {
    __shared__ float2 red[16];
    int tid = threadIdx.x, blk = blockIdx.x;
    SCf sc;
    make_scf(a, b, sc);
    PtCf p;
    make_point(tid, p);

    float zs = (float)grid_zs(blk);
    ItSf is;
    iter_scalars_f(zs, sc, is);
    float IL, ID;
    integrands_f(p, is, sc, IL, ID);
    float sLf = p.wt * IL;
    float sDf = p.wt * ID;
    block_reduce2f(sLf, sDf, red, tid);
    if (tid == 0) {
        W[blk] = (sDf > 0.0f) ? (float)(4.0 * (double)zs * (double)sLf / PI_D) : 1e30f;
    }
}

// ---- Kernel 2: interp init + ONE mega-pass (L,dL,V,V') + Taylor output ----
__global__ __launch_bounds__(1024, 4) void k_newton(const float* Ls, const float* a,
                                                    const float* b, const float* logcoef,
                                                    const float* W, float* out,
                                                    int out_size, int B) {
    __shared__ float red6[16][6];
    __shared__ float wv[16];
    __shared__ int wi[16];
    int tid = threadIdx.x, blk = blockIdx.x;
    SCf sc;
    make_scf(a, b, sc);

    float Ltf = Ls[blk];
    double Lt = (double)Ltf;

    // argmin |Lg - L| over 256 masked entries (first-min tie-break)
    float v = (tid < NGRID) ? fabsf(W[tid] - Ltf) : 3e38f;
    int idx = (tid < NGRID) ? tid : (1 << 30);
    #pragma unroll
    for (int off = 32; off > 0; off >>= 1) {
        float ov = __shfl_xor(v, off);
        int oi = __shfl_xor(idx, off);
        if (ov < v || (ov == v && oi < idx)) { v = ov; idx = oi; }
    }
    if ((tid & 63) == 0) { wv[tid >> 6] = v; wi[tid >> 6] = idx; }
    __syncthreads();
    v = wv[0]; idx = wi[0];
    #pragma unroll
    for (int w = 1; w < 16; ++w) {
        if (wv[w] < v || (wv[w] == v && wi[w] < idx)) { v = wv[w]; idx = wi[w]; }
    }

    // Linear-interp init within the bracketing cell.
    double zs = grid_zs(idx);
    {
        float Lg0 = W[idx];
        if (Lg0 < 1e29f) {
            int nb = (Lg0 <= Ltf) ? idx + 1 : idx - 1;
            if (nb >= 0 && nb < NGRID) {
                float Lg1 = W[nb];
                if (Lg1 < 1e29f && Lg1 != Lg0) {
                    float tf = __fdividef(Ltf - Lg0, Lg1 - Lg0);
                    tf = fminf(fmaxf(tf, 0.0f), 1.0f);
                    zs = zs + (double)tf * (grid_zs(nb) - grid_zs(idx));
                }
            }
        }
    }
    __syncthreads();

    PtCf p;
    make_point(tid, p);

    // ONE pass at zs0: L, dL, Vc, dVc, Vd, dVd.
    ItSf is;
    iter_scalars_f((float)zs, sc, is);
    float omzs = 1.0f - (float)zs;
    float s6[6] = {0,0,0,0,0,0};   // sL, sD, sVc, sdVc, sVd, sdVd
    {
        int kk = (tid < NPTS) ? tid : (NPTS - 1);
        float u = p.u;
        float w2 = u * u, w4 = w2 * w2;
        float z   = is.zs * u;
        float lnz = is.lnzs + p.lnu;
        float z4  = is.zs4 * w4;
        float f = eval_f_f(z, lnz, z4, sc);
        float bv = eval_bv_f(z, sc);
        float ab = fabsf(bv);
        float sg = copysignf(1.0f, bv);
        float dbv = eval_dbv_f(z, sc);
        float inv_f = __fdividef(1.0f, f);
        float Q = eval_Q_f(z, sc);
        float inv_z = is.inv_zs * p.inv_u;
        float df = (4.0f * f - Q) * inv_z - 0.004f * sc.sa * z4;
        float iu2 = p.inv_u * p.inv_u;
        float r4 = iu2 * iu2;
        {   // L and dL integrands
            float sqrtg = ab * rsqrtf(f);
            float fofs = f * is.inv_fs;
            float A = fofs * r4;
            float r = rsqrtf(A - 1.0f);
            float IL = sqrtg * p.y * r;
            float t = z * (2.0f * __fdividef(dbv, bv) - df * inv_f);
            float i1 = A * (is.sdf + 2.0f + t) - r4 * z * df * is.inv_fs - 2.0f - t;
            float ID = i1 * 2.0f * p.y * sqrtg * (r * r * r);
            s6[0] = p.wt * IL;
            s6[1] = p.wt * ID;
        }
        {   // Vc integrand + d/dzs
            float arg = fmaf(-w4 * is.fs, inv_f, 1.0f);      // 1 - w4*fs/f
            float r = rsqrtf(arg);
            float yiu2 = p.y * iu2;
            float Ic = ab * (r - 1.0f) * yiu2;
            float darg = -w4 * inv_f * fmaf(-is.fs * inv_f * df, u, is.dfs);
            float dIc = yiu2 * fmaf(sg * dbv * u, (r - 1.0f),
                                    -0.5f * ab * (r * r * r) * darg);
            s6[2] = p.wt * Ic;
            s6[3] = p.wt * dIc;
        }
        {   // Vd integrand + d/dzs (z = 1-(1-zs)*yd)
            float yd = (float)(Y0C + (double)kk * HD);
            float wyd;
            if (tid >= NPTS)     wyd = 0.0f;
            else if (tid == 0)   wyd = (float)WD0;
            else if (tid == 999) wyd = (float)WD999;
            else                 wyd = (float)HD;
            float zd = fmaf(-omzs, yd, 1.0f);
            float bvd = eval_bv_f(zd, sc);
            float abd = fabsf(bvd);
            float sgd = copysignf(1.0f, bvd);
            float dbvd = eval_dbv_f(zd, sc);
            float izd = __fdividef(1.0f, zd);
            float izd2 = izd * izd;
            float Id = abd * izd2;
            float dId = yd * fmaf(sgd * dbvd, zd, -2.0f * abd) * izd2 * izd;
            s6[4] = wyd * Id;
            s6[5] = wyd * dId;
        }
    }
    block_reduce6f(s6, red6, tid);

    // Scalar epilogue (f64): Newton step + first-order V propagation.
    double L_  = 4.0 * zs * (double)s6[0] / PI_D;
    double dL  = (double)s6[1] / PI_D;
    double zs1 = zs - (L_ - Lt) / dL;
    zs1 = fmin(fmax(zs1, 1e-3), 0.999);
    double dz = zs1 - zs;

    double elc = exp((double)logcoef[0]);
    double Kc = elc * PI_D * 4.0;
    double Kd = elc * PI_D * 2.0;
    double SVc = (double)s6[2], SdVc = (double)s6[3];
    double SVd = (double)s6[4], SdVd = (double)s6[5];
    double C0 = 0.5 * Y0C;
    double Vc  = Kc * SVc / zs;
    double dVc = Kc * (SdVc / zs - SVc / (zs * zs));
    double Vd  = Kd * (1.0 - zs) * (C0 + SVd);
    double dVd = Kd * (-(C0 + SVd) + (1.0 - zs) * SdVd);
    double outv = (Vc - Vd) + dz * (dVc - dVd);

    if (tid == 0) {
        if (out_size >= 2 * B) {   // complex64 layout: interleaved re, im
            out[2 * blk]     = (float)outv;
            out[2 * blk + 1] = 0.0f;
        } else {
            out[blk] = (float)outv;
        }
    }
}

extern "C" void kernel_launch(void* const* d_in, const int* in_sizes, int n_in,
                              void* d_out, int out_size, void* d_ws, size_t ws_size,
                              hipStream_t stream) {
    const float* Ls = (const float*)d_in[0];
    const float* a  = (const float*)d_in[1];
    const float* b  = (const float*)d_in[2];
    const float* lc = (const float*)d_in[3];
    float* W = (float*)d_ws;
    int B = in_sizes[0];

    hipLaunchKernelGGL(k_grid, dim3(NGRID), dim3(1024), 0, stream, a, b, W);
    hipLaunchKernelGGL(k_newton, dim3(B), dim3(1024), 0, stream,
                       Ls, a, b, lc, W, (float*)d_out, out_size, B);
}

// Round 20
// 15.630 us; speedup vs baseline: 2.3950x; 1.5687x over previous
//
#include <hip/hip_runtime.h>
#include <math.h>

#define NPTS 1000
#define NC   64            // coarse init candidates
#define NQ   16            // coarse quadrature points
#define PI_D 3.14159265358979323846

// Fine Y grid: linspace(1e-3, 0.999, 1000). YD grid: linspace(1e-3, 1.0, 1000).
#define HY   ((0.999 - 1e-3) / 999.0)
#define Y0C  (1e-3)
#define HD   ((1.0 - 1e-3) / 999.0)
#define H16  ((0.999 - 1e-3) / 15.0)

// trapz+extrapolation weights (closed form — uniform grid)
#define WY0   (0.5 * HY + Y0C + 0.5 * Y0C * Y0C / HY)
#define WY1   (HY - 0.5 * Y0C * Y0C / HY)
#define WY999 (0.5 * HY + 0.5 * (1.0 - 0.999))
#define WD0   (0.5 * (Y0C + HD))
#define WD999 (0.5 * HD)

struct SCf {
    float c[11], pc[11], bc[6], dbc[5], S, sa;
};

__device__ inline void make_scf(const float* a, const float* b, SCf& s) {
    float af[6], bf[6];
    af[0] = 1.0f; bf[0] = 1.0f;
    #pragma unroll
    for (int i = 0; i < 5; ++i) { af[i+1] = a[i]; bf[i+1] = b[i]; }
    #pragma unroll
    for (int k = 0; k < 11; ++k) s.c[k] = 0.0f;
    #pragma unroll
    for (int i = 0; i < 6; ++i)
        #pragma unroll
        for (int j = 0; j < 6; ++j)
            s.c[i+j] = fmaf(4.0f * af[i], af[j], s.c[i+j]);
    const float INVK[11] = { -0.25f, -1.0f/3.0f, -0.5f, -1.0f, 0.0f,
                              1.0f, 0.5f, 1.0f/3.0f, 0.25f, 0.2f, 1.0f/6.0f };
    float S = 0.0f;
    #pragma unroll
    for (int k = 0; k < 11; ++k) { s.pc[k] = s.c[k] * INVK[k]; S += s.pc[k]; }
    s.S = S;
    float sa = 0.0f;
    #pragma unroll
    for (int i = 0; i < 5; ++i) sa = fmaf(a[i], a[i], sa);
    s.sa = sa;
    #pragma unroll
    for (int i = 0; i < 6; ++i) s.bc[i] = bf[i];
    #pragma unroll
    for (int i = 1; i < 6; ++i) s.dbc[i-1] = (float)i * bf[i];
}

__device__ inline float eval_f_f(float z, float lnz, float z4, const SCf& s) {
    float P = s.pc[10];
    #pragma unroll
    for (int k = 9; k >= 0; --k) P = fmaf(P, z, s.pc[k]);
    return s.S * z4 - P - s.c[4] * z4 * lnz + 0.004f * s.sa * z4 * (1.0f - z);
}
__device__ inline float eval_Q_f(float z, const SCf& s) {
    float Q = s.c[10];
    #pragma unroll
    for (int k = 9; k >= 0; --k) Q = fmaf(Q, z, s.c[k]);
    return Q;
}
__device__ inline float eval_bv_f(float z, const SCf& s) {
    float B = s.bc[5];
    #pragma unroll
    for (int k = 4; k >= 0; --k) B = fmaf(B, z, s.bc[k]);
    return B;
}
__device__ inline float eval_dbv_f(float z, const SCf& s) {
    float D = s.dbc[4];
    #pragma unroll
    for (int k = 3; k >= 0; --k) D = fmaf(D, z, s.dbc[k]);
    return D;
}

struct PtCf { float y, u, lnu, wt, inv_u; };
struct ItSf { float zs, lnzs, zs4, fs, inv_fs, inv_zs, sdf, dfs; };

// Fine-grid points: 2 per thread (512 threads), preserving ILP.
__device__ inline void make_points(int tid, PtCf* p) {
    #pragma unroll
    for (int j = 0; j < 2; ++j) {
        int k = tid + j * 512;
        int kk = (k < NPTS) ? k : (NPTS - 1);
        float y = (float)(Y0C + (double)kk * HY);
        float u = (1.0f - y) * (1.0f + y);
        p[j].y = y;
        p[j].u = u;
        p[j].lnu = __logf(u);
        p[j].inv_u = __fdividef(1.0f, u);
        float wt;
        if (k >= NPTS)      wt = 0.0f;
        else if (k == 0)    wt = (float)WY0;
        else if (k == 1)    wt = (float)WY1;
        else if (k == 999)  wt = (float)WY999;
        else                wt = (float)HY;
        p[j].wt = wt;
    }
}

// Coarse 16-point quadrature point m (same extrapolated-trapz scheme).
__device__ inline void make_coarse_point(int m, PtCf& q) {
    float y = (float)(Y0C + (double)m * H16);
    float u = (1.0f - y) * (1.0f + y);
    q.y = y;
    q.u = u;
    q.lnu = __logf(u);
    q.inv_u = __fdividef(1.0f, u);
    float wt;
    if (m == 0)       wt = (float)(0.5 * H16 + Y0C + 0.5 * Y0C * Y0C / H16);
    else if (m == 1)  wt = (float)(H16 - 0.5 * Y0C * Y0C / H16);
    else if (m == 15) wt = (float)(0.5 * H16 + 0.5 * (1.0 - 0.999));
    else              wt = (float)H16;
    q.wt = wt;
}

__device__ inline void iter_scalars_f(float zs, const SCf& s, ItSf& it) {
    it.zs = zs;
    it.lnzs = __logf(zs);
    float z2 = zs * zs;
    it.zs4 = z2 * z2;
    it.inv_zs = __fdividef(1.0f, zs);
    float f = eval_f_f(zs, it.lnzs, it.zs4, s);
    float Q = eval_Q_f(zs, s);
    float dfs = (4.0f * f - Q) * it.inv_zs - 0.004f * s.sa * it.zs4;
    it.fs = f;
    it.inv_fs = __fdividef(1.0f, f);
    it.dfs = dfs;
    it.sdf = zs * dfs * it.inv_fs;   // zs*dfs/fs
}

// L / dL integrands.
__device__ inline void integrands_f(const PtCf& p, const ItSf& is, const SCf& s,
                                    float& IL, float& ID) {
    float u = p.u;
    float w2 = u * u, w4 = w2 * w2;
    float z   = is.zs * u;
    float lnz = is.lnzs + p.lnu;
    float z4  = is.zs4 * w4;
    float f = eval_f_f(z, lnz, z4, s);
    float bv = eval_bv_f(z, s);
    float inv_f = __fdividef(1.0f, f);
    float sqrtg = fabsf(bv) * rsqrtf(f);
    float fofs = f * is.inv_fs;
    float iu2 = p.inv_u * p.inv_u;
    float r4 = iu2 * iu2;                // zs^4/z^4
    float A = fofs * r4;
    float r = rsqrtf(A - 1.0f);
    IL = sqrtg * p.y * r;
    {
        float Q = eval_Q_f(z, s);
        float inv_z = is.inv_zs * p.inv_u;
        float df = (4.0f * f - Q) * inv_z - 0.004f * s.sa * z4;
        float dbv = eval_dbv_f(z, s);
        float t = z * (2.0f * __fdividef(dbv, bv) - df * inv_f);   // z*dg/g
        float i1 = A * (is.sdf + 2.0f + t) - r4 * z * df * is.inv_fs - 2.0f - t;
        ID = i1 * 2.0f * p.y * sqrtg * (r * r * r);
    }
}

__device__ inline void block_reduce6f(float* s, float (*lds)[6], int tid) {
    #pragma unroll
    for (int off = 32; off > 0; off >>= 1) {
        #pragma unroll
        for (int i = 0; i < 6; ++i) s[i] += __shfl_xor(s[i], off);
    }
    int wid = tid >> 6;
    if ((tid & 63) == 0) {
        #pragma unroll
        for (int i = 0; i < 6; ++i) lds[wid][i] = s[i];
    }
    __syncthreads();
    #pragma unroll
    for (int i = 0; i < 6; ++i) {
        float r = 0.0f;
        #pragma unroll
        for (int w = 0; w < 8; ++w) r += lds[w][i];
        s[i] = r;
    }
    __syncthreads();
}

__device__ inline double cand_zs(int i) {
    return 0.05 + (double)i * (0.999 - 0.05) / (double)(NC - 1);
}

// ---------------- Single kernel: per-block coarse init + Newton-Taylor V ----------------
__global__ __launch_bounds__(512, 4) void k_solve(const float* Ls, const float* a,
                                                  const float* b, const float* logcoef,
                                                  float* out, int out_size, int B) {
    __shared__ float Lc[NC];
    __shared__ float red6[8][6];
    int tid = threadIdx.x, blk = blockIdx.x;
    SCf sc;
    make_scf(a, b, sc);

    // ---- PHASE A: per-block coarse Lg table (64 candidates x 16-pt quadrature) ----
    {
        int c = tid >> 3;        // candidate 0..63
        int sub = tid & 7;       // 8 threads per candidate
        float zc = (float)cand_zs(c);
        ItSf isc;
        iter_scalars_f(zc, sc, isc);
        float sL = 0.0f, sD = 0.0f;
        #pragma unroll
        for (int j = 0; j < 2; ++j) {
            int m = sub + j * 8;
            PtCf q;
            make_coarse_point(m, q);
            float IL, ID;
            integrands_f(q, isc, sc, IL, ID);
            sL = fmaf(q.wt, IL, sL);
            sD = fmaf(q.wt, ID, sD);
        }
        #pragma unroll
        for (int off = 1; off < 8; off <<= 1) {
            sL += __shfl_xor(sL, off);
            sD += __shfl_xor(sD, off);
        }
        if (sub == 0) {
            Lc[c] = (sD > 0.0f) ? (float)(4.0 * (double)zc * (double)sL / PI_D) : 1e30f;
        }
    }
    __syncthreads();

    float Ltf = Ls[blk];
    double Lt = (double)Ltf;

    // ---- PHASE B: 64-lane argmin (each wave redundantly; butterfly -> all lanes) ----
    int lane = tid & 63;
    float lv = Lc[lane];
    float v = (lv < 1e29f) ? fabsf(lv - Ltf) : 3e38f;
    int idx = lane;
    #pragma unroll
    for (int off = 32; off > 0; off >>= 1) {
        float ov = __shfl_xor(v, off);
        int oi = __shfl_xor(idx, off);
        if (ov < v || (ov == v && oi < idx)) { v = ov; idx = oi; }
    }
    // Linear-interp init within the bracketing cell.
    double zs = cand_zs(idx);
    {
        float Lg0 = Lc[idx];
        if (Lg0 < 1e29f) {
            int nb = (Lg0 <= Ltf) ? idx + 1 : idx - 1;
            if (nb >= 0 && nb < NC) {
                float Lg1 = Lc[nb];
                if (Lg1 < 1e29f && Lg1 != Lg0) {
                    float tf = __fdividef(Ltf - Lg0, Lg1 - Lg0);
                    tf = fminf(fmaxf(tf, 0.0f), 1.0f);
                    zs = zs + (double)tf * (cand_zs(nb) - cand_zs(idx));
                }
            }
        }
    }
    __syncthreads();

    // ---- PHASE C: ONE fine mega-pass at zs0 (L, dL, Vc, dVc, Vd, dVd) ----
    PtCf p[2];
    make_points(tid, p);
    ItSf is;
    iter_scalars_f((float)zs, sc, is);
    float omzs = 1.0f - (float)zs;
    float s6[6] = {0,0,0,0,0,0};   // sL, sD, sVc, sdVc, sVd, sdVd
    #pragma unroll
    for (int j = 0; j < 2; ++j) {
        int k = tid + j * 512;
        int kk = (k < NPTS) ? k : (NPTS - 1);
        float u = p[j].u;
        float w2 = u * u, w4 = w2 * w2;
        float z   = is.zs * u;
        float lnz = is.lnzs + p[j].lnu;
        float z4  = is.zs4 * w4;
        float f = eval_f_f(z, lnz, z4, sc);
        float bv = eval_bv_f(z, sc);
        float ab = fabsf(bv);
        float sg = copysignf(1.0f, bv);
        float dbv = eval_dbv_f(z, sc);
        float inv_f = __fdividef(1.0f, f);
        float Q = eval_Q_f(z, sc);
        float inv_z = is.inv_zs * p[j].inv_u;
        float df = (4.0f * f - Q) * inv_z - 0.004f * sc.sa * z4;
        float iu2 = p[j].inv_u * p[j].inv_u;
        float r4 = iu2 * iu2;
        {   // L and dL integrands
            float sqrtg = ab * rsqrtf(f);
            float fofs = f * is.inv_fs;
            float A = fofs * r4;
            float r = rsqrtf(A - 1.0f);
            float IL = sqrtg * p[j].y * r;
            float t = z * (2.0f * __fdividef(dbv, bv) - df * inv_f);
            float i1 = A * (is.sdf + 2.0f + t) - r4 * z * df * is.inv_fs - 2.0f - t;
            float ID = i1 * 2.0f * p[j].y * sqrtg * (r * r * r);
            s6[0] = fmaf(p[j].wt, IL, s6[0]);
            s6[1] = fmaf(p[j].wt, ID, s6[1]);
        }
        {   // Vc integrand + d/dzs
            float arg = fmaf(-w4 * is.fs, inv_f, 1.0f);      // 1 - w4*fs/f
            float r = rsqrtf(arg);
            float yiu2 = p[j].y * iu2;
            float Ic = ab * (r - 1.0f) * yiu2;
            float darg = -w4 * inv_f * fmaf(-is.fs * inv_f * df, u, is.dfs);
            float dIc = yiu2 * fmaf(sg * dbv * u, (r - 1.0f),
                                    -0.5f * ab * (r * r * r) * darg);
            s6[2] = fmaf(p[j].wt, Ic, s6[2]);
            s6[3] = fmaf(p[j].wt, dIc, s6[3]);
        }
        {   // Vd integrand + d/dzs (z = 1-(1-zs)*yd)
            float yd = (float)(Y0C + (double)kk * HD);
            float wyd;
            if (k >= NPTS)      wyd = 0.0f;
            else if (k == 0)    wyd = (float)WD0;
            else if (k == 999)  wyd = (float)WD999;
            else                wyd = (float)HD;
            float zd = fmaf(-omzs, yd, 1.0f);
            float bvd = eval_bv_f(zd, sc);
            float abd = fabsf(bvd);
            float sgd = copysignf(1.0f, bvd);
            float dbvd = eval_dbv_f(zd, sc);
            float izd = __fdividef(1.0f, zd);
            float izd2 = izd * izd;
            float Id = abd * izd2;
            float dId = yd * fmaf(sgd * dbvd, zd, -2.0f * abd) * izd2 * izd;
            s6[4] = fmaf(wyd, Id, s6[4]);
            s6[5] = fmaf(wyd, dId, s6[5]);
        }
    }
    block_reduce6f(s6, red6, tid);

    // ---- PHASE D: scalar epilogue (f64) — Newton step + first-order V propagation ----
    double L_  = 4.0 * zs * (double)s6[0] / PI_D;
    double dL  = (double)s6[1] / PI_D;
    double zs1 = zs - (L_ - Lt) / dL;
    zs1 = fmin(fmax(zs1, 1e-3), 0.999);
    double dz = zs1 - zs;

    double elc = exp((double)logcoef[0]);
    double Kc = elc * PI_D * 4.0;
    double Kd = elc * PI_D * 2.0;
    double SVc = (double)s6[2], SdVc = (double)s6[3];
    double SVd = (double)s6[4], SdVd = (double)s6[5];
    double C0 = 0.5 * Y0C;
    double Vc  = Kc * SVc / zs;
    double dVc = Kc * (SdVc / zs - SVc / (zs * zs));
    double Vd  = Kd * (1.0 - zs) * (C0 + SVd);
    double dVd = Kd * (-(C0 + SVd) + (1.0 - zs) * SdVd);
    double outv = (Vc - Vd) + dz * (dVc - dVd);

    if (tid == 0) {
        if (out_size >= 2 * B) {   // complex64 layout: interleaved re, im
            out[2 * blk]     = (float)outv;
            out[2 * blk + 1] = 0.0f;
        } else {
            out[blk] = (float)outv;
        }
    }
}

extern "C" void kernel_launch(void* const* d_in, const int* in_sizes, int n_in,
                              void* d_out, int out_size, void* d_ws, size_t ws_size,
                              hipStream_t stream) {
    const float* Ls = (const float*)d_in[0];
    const float* a  = (const float*)d_in[1];
    const float* b  = (const float*)d_in[2];
    const float* lc = (const float*)d_in[3];
    int B = in_sizes[0];

    hipLaunchKernelGGL(k_solve, dim3(B), dim3(512), 0, stream,
                       Ls, a, b, lc, (float*)d_out, out_size, B);
}

// Round 21
// 14.177 us; speedup vs baseline: 2.6404x; 1.1025x over previous
//
#include <hip/hip_runtime.h>
#include <math.h>

#define NPTS 1000
#define NC   64            // coarse init candidates
#define PI_D 3.14159265358979323846

// Fine Y grid: linspace(1e-3, 0.999, 1000). YD grid: linspace(1e-3, 1.0, 1000).
#define HY   ((0.999 - 1e-3) / 999.0)
#define Y0C  (1e-3)
#define HD   ((1.0 - 1e-3) / 999.0)
#define H16  ((0.999 - 1e-3) / 15.0)

// trapz+extrapolation weights (closed form — uniform grid)
#define WY0   (0.5 * HY + Y0C + 0.5 * Y0C * Y0C / HY)
#define WY1   (HY - 0.5 * Y0C * Y0C / HY)
#define WY999 (0.5 * HY + 0.5 * (1.0 - 0.999))
#define WD0   (0.5 * (Y0C + HD))
#define WD999 (0.5 * HD)

struct SCf {
    float c[11], pc[11], bc[6], dbc[5], S, sa;
};

__device__ inline void make_scf(const float* a, const float* b, SCf& s) {
    float af[6], bf[6];
    af[0] = 1.0f; bf[0] = 1.0f;
    #pragma unroll
    for (int i = 0; i < 5; ++i) { af[i+1] = a[i]; bf[i+1] = b[i]; }
    #pragma unroll
    for (int k = 0; k < 11; ++k) s.c[k] = 0.0f;
    #pragma unroll
    for (int i = 0; i < 6; ++i)
        #pragma unroll
        for (int j = 0; j < 6; ++j)
            s.c[i+j] = fmaf(4.0f * af[i], af[j], s.c[i+j]);
    const float INVK[11] = { -0.25f, -1.0f/3.0f, -0.5f, -1.0f, 0.0f,
                              1.0f, 0.5f, 1.0f/3.0f, 0.25f, 0.2f, 1.0f/6.0f };
    float S = 0.0f;
    #pragma unroll
    for (int k = 0; k < 11; ++k) { s.pc[k] = s.c[k] * INVK[k]; S += s.pc[k]; }
    s.S = S;
    float sa = 0.0f;
    #pragma unroll
    for (int i = 0; i < 5; ++i) sa = fmaf(a[i], a[i], sa);
    s.sa = sa;
    #pragma unroll
    for (int i = 0; i < 6; ++i) s.bc[i] = bf[i];
    #pragma unroll
    for (int i = 1; i < 6; ++i) s.dbc[i-1] = (float)i * bf[i];
}

__device__ inline float eval_f_f(float z, float lnz, float z4, const SCf& s) {
    float P = s.pc[10];
    #pragma unroll
    for (int k = 9; k >= 0; --k) P = fmaf(P, z, s.pc[k]);
    return s.S * z4 - P - s.c[4] * z4 * lnz + 0.004f * s.sa * z4 * (1.0f - z);
}
__device__ inline float eval_Q_f(float z, const SCf& s) {
    float Q = s.c[10];
    #pragma unroll
    for (int k = 9; k >= 0; --k) Q = fmaf(Q, z, s.c[k]);
    return Q;
}
__device__ inline float eval_bv_f(float z, const SCf& s) {
    float B = s.bc[5];
    #pragma unroll
    for (int k = 4; k >= 0; --k) B = fmaf(B, z, s.bc[k]);
    return B;
}
__device__ inline float eval_dbv_f(float z, const SCf& s) {
    float D = s.dbc[4];
    #pragma unroll
    for (int k = 3; k >= 0; --k) D = fmaf(D, z, s.dbc[k]);
    return D;
}

struct PtCf { float y, u, lnu, wt, inv_u; };
struct ItSf { float zs, lnzs, zs4, fs, inv_fs, inv_zs, sdf, dfs; };

// Fine-grid points: 2 per thread (512 threads), preserving ILP.
__device__ inline void make_points(int tid, PtCf* p) {
    #pragma unroll
    for (int j = 0; j < 2; ++j) {
        int k = tid + j * 512;
        int kk = (k < NPTS) ? k : (NPTS - 1);
        float y = (float)(Y0C + (double)kk * HY);
        float u = (1.0f - y) * (1.0f + y);
        p[j].y = y;
        p[j].u = u;
        p[j].lnu = __logf(u);
        p[j].inv_u = __fdividef(1.0f, u);
        float wt;
        if (k >= NPTS)      wt = 0.0f;
        else if (k == 0)    wt = (float)WY0;
        else if (k == 1)    wt = (float)WY1;
        else if (k == 999)  wt = (float)WY999;
        else                wt = (float)HY;
        p[j].wt = wt;
    }
}

// Coarse 16-point quadrature point m (same extrapolated-trapz scheme).
__device__ inline void make_coarse_point(int m, PtCf& q) {
    float y = (float)(Y0C + (double)m * H16);
    float u = (1.0f - y) * (1.0f + y);
    q.y = y;
    q.u = u;
    q.lnu = __logf(u);
    q.inv_u = __fdividef(1.0f, u);
    float wt;
    if (m == 0)       wt = (float)(0.5 * H16 + Y0C + 0.5 * Y0C * Y0C / H16);
    else if (m == 1)  wt = (float)(H16 - 0.5 * Y0C * Y0C / H16);
    else if (m == 15) wt = (float)(0.5 * H16 + 0.5 * (1.0 - 0.999));
    else              wt = (float)H16;
    q.wt = wt;
}

__device__ inline void iter_scalars_f(float zs, const SCf& s, ItSf& it) {
    it.zs = zs;
    it.lnzs = __logf(zs);
    float z2 = zs * zs;
    it.zs4 = z2 * z2;
    it.inv_zs = __fdividef(1.0f, zs);
    float f = eval_f_f(zs, it.lnzs, it.zs4, s);
    float Q = eval_Q_f(zs, s);
    float dfs = (4.0f * f - Q) * it.inv_zs - 0.004f * s.sa * it.zs4;
    it.fs = f;
    it.inv_fs = __fdividef(1.0f, f);
    it.dfs = dfs;
    it.sdf = zs * dfs * it.inv_fs;   // zs*dfs/fs
}

// L-only integrand (coarse phase A — no dL chain).
__device__ inline float integrand_L_f(const PtCf& p, const ItSf& is, const SCf& s) {
    float u = p.u;
    float w2 = u * u, w4 = w2 * w2;
    float z   = is.zs * u;
    float lnz = is.lnzs + p.lnu;
    float z4  = is.zs4 * w4;
    float f = eval_f_f(z, lnz, z4, s);
    float bv = eval_bv_f(z, s);
    float sqrtg = fabsf(bv) * rsqrtf(f);
    float fofs = f * is.inv_fs;
    float iu2 = p.inv_u * p.inv_u;
    float r4 = iu2 * iu2;
    float A = fofs * r4;
    float r = rsqrtf(A - 1.0f);
    return sqrtg * p.y * r;
}

__device__ inline void block_reduce6f(float* s, float (*lds)[6], int tid) {
    #pragma unroll
    for (int off = 32; off > 0; off >>= 1) {
        #pragma unroll
        for (int i = 0; i < 6; ++i) s[i] += __shfl_xor(s[i], off);
    }
    int wid = tid >> 6;
    if ((tid & 63) == 0) {
        #pragma unroll
        for (int i = 0; i < 6; ++i) lds[wid][i] = s[i];
    }
    __syncthreads();
    #pragma unroll
    for (int i = 0; i < 6; ++i) {
        float r = 0.0f;
        #pragma unroll
        for (int w = 0; w < 8; ++w) r += lds[w][i];
        s[i] = r;
    }
    __syncthreads();
}

__device__ inline double cand_zs(int i) {
    return 0.05 + (double)i * (0.999 - 0.05) / (double)(NC - 1);
}

// ---------------- Single kernel: per-block coarse init + Newton-Taylor V ----------------
__global__ __launch_bounds__(512, 4) void k_solve(const float* Ls, const float* a,
                                                  const float* b, const float* logcoef,
                                                  float* out, int out_size, int B) {
    __shared__ float Lc[NC];
    __shared__ float red6[8][6];
    int tid = threadIdx.x, blk = blockIdx.x;
    SCf sc;
    make_scf(a, b, sc);

    // ---- PHASE A: per-block coarse L table (64 candidates x 16-pt quadrature, L only) ----
    {
        int c = tid >> 3;        // candidate 0..63
        int sub = tid & 7;       // 8 threads per candidate
        float zc = (float)cand_zs(c);
        ItSf isc;
        iter_scalars_f(zc, sc, isc);
        float sL = 0.0f;
        #pragma unroll
        for (int j = 0; j < 2; ++j) {
            int m = sub + j * 8;
            PtCf q;
            make_coarse_point(m, q);
            sL = fmaf(q.wt, integrand_L_f(q, isc, sc), sL);
        }
        #pragma unroll
        for (int off = 1; off < 8; off <<= 1) sL += __shfl_xor(sL, off);
        if (sub == 0) Lc[c] = (float)(4.0 * (double)zc * (double)sL / PI_D);
    }
    __syncthreads();

    float Ltf = Ls[blk];
    double Lt = (double)Ltf;

    // ---- PHASE B: rising-branch mask via argmax, then masked argmin (64-lane) ----
    int lane = tid & 63;
    float lv = Lc[lane];
    // argmax (first-max tie-break)
    float mv = lv;
    int mi = lane;
    #pragma unroll
    for (int off = 32; off > 0; off >>= 1) {
        float ov = __shfl_xor(mv, off);
        int oi = __shfl_xor(mi, off);
        if (ov > mv || (ov == mv && oi < mi)) { mv = ov; mi = oi; }
    }
    // masked argmin |Lc - Lt| over lanes <= mi (rising branch)
    float v = (lane <= mi) ? fabsf(lv - Ltf) : 3e38f;
    int idx = (lane <= mi) ? lane : (1 << 30);
    #pragma unroll
    for (int off = 32; off > 0; off >>= 1) {
        float ov = __shfl_xor(v, off);
        int oi = __shfl_xor(idx, off);
        if (ov < v || (ov == v && oi < idx)) { v = ov; idx = oi; }
    }
    // Linear-interp init within the bracketing cell (neighbors restricted to rising branch).
    double zs = cand_zs(idx);
    {
        float Lg0 = Lc[idx];
        int nb = (Lg0 <= Ltf) ? idx + 1 : idx - 1;
        if (nb >= 0 && nb <= mi) {
            float Lg1 = Lc[nb];
            if (Lg1 != Lg0) {
                float tf = __fdividef(Ltf - Lg0, Lg1 - Lg0);
                tf = fminf(fmaxf(tf, 0.0f), 1.0f);
                zs = zs + (double)tf * (cand_zs(nb) - cand_zs(idx));
            }
        }
    }
    __syncthreads();

    // ---- PHASE C: ONE fine mega-pass at zs0 (L, dL, Vc, dVc, Vd, dVd) ----
    PtCf p[2];
    make_points(tid, p);
    ItSf is;
    iter_scalars_f((float)zs, sc, is);
    float omzs = 1.0f - (float)zs;
    float s6[6] = {0,0,0,0,0,0};   // sL, sD, sVc, sdVc, sVd, sdVd
    #pragma unroll
    for (int j = 0; j < 2; ++j) {
        int k = tid + j * 512;
        int kk = (k < NPTS) ? k : (NPTS - 1);
        float u = p[j].u;
        float w2 = u * u, w4 = w2 * w2;
        float z   = is.zs * u;
        float lnz = is.lnzs + p[j].lnu;
        float z4  = is.zs4 * w4;
        float f = eval_f_f(z, lnz, z4, sc);
        float bv = eval_bv_f(z, sc);
        float ab = fabsf(bv);
        float sg = copysignf(1.0f, bv);
        float dbv = eval_dbv_f(z, sc);
        float inv_f = __fdividef(1.0f, f);
        float Q = eval_Q_f(z, sc);
        float inv_z = is.inv_zs * p[j].inv_u;
        float df = (4.0f * f - Q) * inv_z - 0.004f * sc.sa * z4;
        float iu2 = p[j].inv_u * p[j].inv_u;
        float r4 = iu2 * iu2;
        {   // L and dL integrands
            float sqrtg = ab * rsqrtf(f);
            float fofs = f * is.inv_fs;
            float A = fofs * r4;
            float r = rsqrtf(A - 1.0f);
            float IL = sqrtg * p[j].y * r;
            float t = z * (2.0f * __fdividef(dbv, bv) - df * inv_f);
            float i1 = A * (is.sdf + 2.0f + t) - r4 * z * df * is.inv_fs - 2.0f - t;
            float ID = i1 * 2.0f * p[j].y * sqrtg * (r * r * r);
            s6[0] = fmaf(p[j].wt, IL, s6[0]);
            s6[1] = fmaf(p[j].wt, ID, s6[1]);
        }
        {   // Vc integrand + d/dzs
            float arg = fmaf(-w4 * is.fs, inv_f, 1.0f);      // 1 - w4*fs/f
            float r = rsqrtf(arg);
            float yiu2 = p[j].y * iu2;
            float Ic = ab * (r - 1.0f) * yiu2;
            float darg = -w4 * inv_f * fmaf(-is.fs * inv_f * df, u, is.dfs);
            float dIc = yiu2 * fmaf(sg * dbv * u, (r - 1.0f),
                                    -0.5f * ab * (r * r * r) * darg);
            s6[2] = fmaf(p[j].wt, Ic, s6[2]);
            s6[3] = fmaf(p[j].wt, dIc, s6[3]);
        }
        {   // Vd integrand + d/dzs (z = 1-(1-zs)*yd)
            float yd = (float)(Y0C + (double)kk * HD);
            float wyd;
            if (k >= NPTS)      wyd = 0.0f;
            else if (k == 0)    wyd = (float)WD0;
            else if (k == 999)  wyd = (float)WD999;
            else                wyd = (float)HD;
            float zd = fmaf(-omzs, yd, 1.0f);
            float bvd = eval_bv_f(zd, sc);
            float abd = fabsf(bvd);
            float sgd = copysignf(1.0f, bvd);
            float dbvd = eval_dbv_f(zd, sc);
            float izd = __fdividef(1.0f, zd);
            float izd2 = izd * izd;
            float Id = abd * izd2;
            float dId = yd * fmaf(sgd * dbvd, zd, -2.0f * abd) * izd2 * izd;
            s6[4] = fmaf(wyd, Id, s6[4]);
            s6[5] = fmaf(wyd, dId, s6[5]);
        }
    }
    block_reduce6f(s6, red6, tid);

    // ---- PHASE D: scalar epilogue (f64) — Newton step + first-order V propagation ----
    double L_  = 4.0 * zs * (double)s6[0] / PI_D;
    double dL  = (double)s6[1] / PI_D;
    double zs1 = zs - (L_ - Lt) / dL;
    zs1 = fmin(fmax(zs1, 1e-3), 0.999);
    double dz = zs1 - zs;

    double elc = exp((double)logcoef[0]);
    double Kc = elc * PI_D * 4.0;
    double Kd = elc * PI_D * 2.0;
    double SVc = (double)s6[2], SdVc = (double)s6[3];
    double SVd = (double)s6[4], SdVd = (double)s6[5];
    double C0 = 0.5 * Y0C;
    double Vc  = Kc * SVc / zs;
    double dVc = Kc * (SdVc / zs - SVc / (zs * zs));
    double Vd  = Kd * (1.0 - zs) * (C0 + SVd);
    double dVd = Kd * (-(C0 + SVd) + (1.0 - zs) * SdVd);
    double outv = (Vc - Vd) + dz * (dVc - dVd);

    if (tid == 0) {
        if (out_size >= 2 * B) {   // complex64 layout: interleaved re, im
            out[2 * blk]     = (float)outv;
            out[2 * blk + 1] = 0.0f;
        } else {
            out[blk] = (float)outv;
        }
    }
}

extern "C" void kernel_launch(void* const* d_in, const int* in_sizes, int n_in,
                              void* d_out, int out_size, void* d_ws, size_t ws_size,
                              hipStream_t stream) {
    const float* Ls = (const float*)d_in[0];
    const float* a  = (const float*)d_in[1];
    const float* b  = (const float*)d_in[2];
    const float* lc = (const float*)d_in[3];
    int B = in_sizes[0];

    hipLaunchKernelGGL(k_solve, dim3(B), dim3(512), 0, stream,
                       Ls, a, b, lc, (float*)d_out, out_size, B);
}